// Round 1
// baseline (344.131 us; speedup 1.0000x reference)
//
#include <hip/hip_runtime.h>
#include <math.h>

#define M0 128
#define M1 64
#define M2 32
#define DIMN 480      // 128 + 3*64 + 5*32
#define MSGC 64
#define NBLK 3
#define RBFD 32
#define NT 2048       // r-table resolution
#define FCUT 5.0f

// ---------- per-edge geometric features: sh[9], fcut ----------
__global__ void k_edge(const float* __restrict__ ew, const float* __restrict__ ev,
                       const int* __restrict__ dst, float* __restrict__ shf,
                       int* __restrict__ counts, int E) {
    int e = blockIdx.x * blockDim.x + threadIdx.x;
    if (e >= E) return;
    float len = ew[e];
    float inv = 1.0f / fmaxf(len, 1e-8f);
    float x = ev[e * 3 + 0] * inv;
    float y = ev[e * 3 + 1] * inv;
    float z = ev[e * 3 + 2] * inv;
    const float s3 = 1.7320508075688772f, s5 = 2.23606797749979f, s15 = 3.872983346207417f;
    float* o = shf + (size_t)e * 10;
    o[0] = 1.0f;
    o[1] = s3 * x;
    o[2] = s3 * y;
    o[3] = s3 * z;
    o[4] = s15 * x * y;
    o[5] = s15 * y * z;
    o[6] = 0.5f * s5 * (3.0f * z * z - 1.0f);
    o[7] = s15 * x * z;
    o[8] = 0.5f * s15 * (x * x - y * y);
    float t = fminf(len / FCUT, 1.0f);
    o[9] = 0.5f * (cosf(3.14159265358979323846f * t) + 1.0f);
    atomicAdd(&counts[dst[e]], 1);
}

// ---------- exclusive prefix scan of counts (single block) ----------
__global__ void k_scan(const int* __restrict__ counts, int* __restrict__ offs,
                       int* __restrict__ cursor, int n) {
    __shared__ int buf[4096];
    for (int i = threadIdx.x; i < n; i += blockDim.x) buf[i] = counts[i];
    __syncthreads();
    for (int d = 1; d < n; d <<= 1) {
        int vals[4];
        int k = 0;
        for (int i = threadIdx.x; i < n; i += blockDim.x, ++k)
            vals[k] = (i >= d) ? buf[i - d] : 0;
        __syncthreads();
        k = 0;
        for (int i = threadIdx.x; i < n; i += blockDim.x, ++k)
            buf[i] += vals[k];
        __syncthreads();
    }
    for (int i = threadIdx.x; i < n; i += blockDim.x) {
        int excl = (i == 0) ? 0 : buf[i - 1];
        offs[i] = excl;
        cursor[i] = excl;
    }
    if (threadIdx.x == 0) offs[n] = buf[n - 1];
}

// ---------- scatter edge ids into dst-sorted order ----------
__global__ void k_perm(const int* __restrict__ dst, int* __restrict__ cursor,
                       int* __restrict__ perm, int E) {
    int e = blockIdx.x * blockDim.x + threadIdx.x;
    if (e >= E) return;
    int p = atomicAdd(&cursor[dst[e]], 1);
    perm[p] = e;
}

// ---------- x init: x[:, :128] = (z_emb[z] @ W_in) * mask ; rest 0 ----------
__global__ __launch_bounds__(128) void k_initx(const int* __restrict__ z,
                                               const float* __restrict__ mask,
                                               const float* __restrict__ zemb,
                                               const float* __restrict__ Win,
                                               float* __restrict__ x) {
    int n = blockIdx.x;
    __shared__ float zf[M0];
    int zi = z[n];
    for (int k = threadIdx.x; k < M0; k += blockDim.x) zf[k] = zemb[zi * M0 + k];
    __syncthreads();
    int j = threadIdx.x;
    float acc = 0.0f;
    for (int k = 0; k < M0; ++k) acc += zf[k] * Win[k * M0 + j];
    float fm = mask[n];
    x[(size_t)n * DIMN + j] = acc * fm;
    for (int t = M0 + j; t < DIMN; t += M0) x[(size_t)n * DIMN + t] = 0.0f;
}

// ---------- r-table: r(len) = silu(rbf(len)@rW1+rb1)@rW2+rb2, len on NT grid ----------
__global__ __launch_bounds__(64) void k_rtab(const float* __restrict__ rW1,
                                             const float* __restrict__ rb1,
                                             const float* __restrict__ rW2,
                                             const float* __restrict__ rb2,
                                             float* __restrict__ rtab) {
    int row = blockIdx.x;           // 0 .. NBLK*NT-1
    int b = row / NT, t = row % NT;
    float len = (float)t * (FCUT / (float)(NT - 1));
    __shared__ float rb[RBFD];
    __shared__ float hh[64];
    int j = threadIdx.x;
    if (j < RBFD) {
        float c = (float)j * (FCUT / (float)(RBFD - 1));
        float w = FCUT / (float)(RBFD - 1);
        float d0 = (fminf(len, FCUT) - c) / w;
        rb[j] = expf(-0.5f * d0 * d0);
    }
    __syncthreads();
    const float* W1 = rW1 + b * RBFD * 64;
    float a = rb1[b * 64 + j];
    for (int k = 0; k < RBFD; ++k) a += rb[k] * W1[k * 64 + j];
    hh[j] = a / (1.0f + expf(-a));    // silu
    __syncthreads();
    const float* W2 = rW2 + b * 64 * 192;
    for (int c = j; c < 192; c += 64) {
        float r = rb2[b * 192 + c];
        for (int k = 0; k < 64; ++k) r += hh[k] * W2[k * 192 + c];
        rtab[((size_t)b * NT + t) * 192 + c] = r;
    }
}

// ---------- node projection: P = x[:, :128] @ Wp[b] ----------
__global__ __launch_bounds__(192) void k_proj(const float* __restrict__ x,
                                              const float* __restrict__ Wp,
                                              float* __restrict__ P) {
    int n = blockIdx.x;
    __shared__ float s[M0];
    for (int k = threadIdx.x; k < M0; k += blockDim.x) s[k] = x[(size_t)n * DIMN + k];
    __syncthreads();
    int j = threadIdx.x;   // 0..191
    float acc = 0.0f;
    for (int k = 0; k < M0; ++k) acc += s[k] * Wp[k * 192 + j];
    P[(size_t)n * 192 + j] = acc;
}

// ---------- per-node message gather + Wo application (one wave per node) ----------
__global__ __launch_bounds__(64) void k_node(const float* __restrict__ P,
                                             const float* __restrict__ rtab,
                                             const float* __restrict__ shf,
                                             const float* __restrict__ ew,
                                             const int* __restrict__ src_arr,
                                             const int* __restrict__ offs,
                                             const int* __restrict__ perm,
                                             const float* __restrict__ Wo0,
                                             const float* __restrict__ Wo1,
                                             const float* __restrict__ Wo2,
                                             const float* __restrict__ res_scale, int b,
                                             float* __restrict__ x) {
    int n = blockIdx.x;
    int j = threadIdx.x;   // 0..63
    int e0 = offs[n], e1 = offs[n + 1];
    float m0 = 0.0f;
    float m1a[3] = {0, 0, 0};
    float m2a[5] = {0, 0, 0, 0, 0};
    __shared__ float mbuf[576];

    for (int ii = e0; ii < e1; ++ii) {
        int e = perm[ii];
        int src = src_arr[e];
        float len = ew[e];
        const float* sf = shf + (size_t)e * 10;
        float sh1 = sf[1], sh2 = sf[2], sh3 = sf[3], sh4 = sf[4];
        float sh5 = sf[5], sh6 = sf[6], sh7 = sf[7], sh8 = sf[8];
        float fc = sf[9];
        float u = fminf(len, FCUT) * ((float)(NT - 1) / FCUT);
        int ti = (int)u;
        ti = min(ti, NT - 2);
        float fr = u - (float)ti;
        const float* r0 = rtab + (size_t)ti * 192;
        const float* r1 = r0 + 192;
        const float* Ps = P + (size_t)src * 192;

        float ra = r0[j] + fr * (r1[j] - r0[j]);
        float w0 = Ps[j] * ra * fc;
        m0 += w0;

        float rb_ = r0[64 + j] + fr * (r1[64 + j] - r0[64 + j]);
        float w1 = Ps[64 + j] * rb_ * fc;
        m1a[0] += w1 * sh1;
        m1a[1] += w1 * sh2;
        m1a[2] += w1 * sh3;

        float rc = r0[128 + j] + fr * (r1[128 + j] - r0[128 + j]);
        float w2 = Ps[128 + j] * rc * fc;
        m2a[0] += w2 * sh4;
        m2a[1] += w2 * sh5;
        m2a[2] += w2 * sh6;
        m2a[3] += w2 * sh7;
        m2a[4] += w2 * sh8;
    }

    mbuf[j] = m0;
    for (int d = 0; d < 3; ++d) mbuf[64 + j * 3 + d] = m1a[d];
    for (int d = 0; d < 5; ++d) mbuf[64 + 192 + j * 5 + d] = m2a[d];
    __syncthreads();

    float rs = res_scale[b];
    float* xn = x + (size_t)n * DIMN;

    // u0 = m0 @ Wo0   (64 -> 128)
    for (int o = j; o < M0; o += 64) {
        float acc = 0.0f;
        for (int c = 0; c < 64; ++c) acc += mbuf[c] * Wo0[c * M0 + o];
        xn[o] += rs * acc;
    }
    // u1[k][d] = sum_c m1[c][d] * Wo1[c][k]   (lane j = k)
    {
        int k = j;
        float a0 = 0, a1 = 0, a2 = 0;
        for (int c = 0; c < 64; ++c) {
            float wv = Wo1[c * M1 + k];
            a0 += mbuf[64 + c * 3 + 0] * wv;
            a1 += mbuf[64 + c * 3 + 1] * wv;
            a2 += mbuf[64 + c * 3 + 2] * wv;
        }
        xn[M0 + k * 3 + 0] += rs * a0;
        xn[M0 + k * 3 + 1] += rs * a1;
        xn[M0 + k * 3 + 2] += rs * a2;
    }
    // u2[k][d] = sum_c m2[c][d] * Wo2[c][k]   (lanes 0..31)
    if (j < M2) {
        int k = j;
        float a[5] = {0, 0, 0, 0, 0};
        for (int c = 0; c < 64; ++c) {
            float wv = Wo2[c * M2 + k];
            for (int d = 0; d < 5; ++d) a[d] += mbuf[256 + c * 5 + d] * wv;
        }
        for (int d = 0; d < 5; ++d) xn[320 + k * 5 + d] += rs * a[d];
    }
}

// ---------- final irrep norm + mask ----------
__global__ __launch_bounds__(64) void k_norm(const float* __restrict__ x,
                                             const float* __restrict__ mask,
                                             float* __restrict__ out) {
    int n = blockIdx.x;
    int j = threadIdx.x;
    const float* xn = x + (size_t)n * DIMN;
    float s0 = 0, s1 = 0, s2 = 0;
    for (int c = j; c < 128; c += 64) { float v = xn[c]; s0 += v * v; }
    for (int c = j; c < 192; c += 64) { float v = xn[128 + c]; s1 += v * v; }
    for (int c = j; c < 160; c += 64) { float v = xn[320 + c]; s2 += v * v; }
    for (int d = 32; d > 0; d >>= 1) {
        s0 += __shfl_down(s0, d);
        s1 += __shfl_down(s1, d);
        s2 += __shfl_down(s2, d);
    }
    __shared__ float inv0, inv1, inv2;
    if (j == 0) {
        inv0 = rsqrtf(s0 / (float)M0 + 1e-6f);
        inv1 = rsqrtf(s1 / (float)M1 + 1e-6f);
        inv2 = rsqrtf(s2 / (float)M2 + 1e-6f);
    }
    __syncthreads();
    float fm = mask[n];
    float* on = out + (size_t)n * DIMN;
    for (int c = j; c < 128; c += 64) on[c] = xn[c] * inv0 * fm;
    for (int c = j; c < 192; c += 64) on[128 + c] = xn[128 + c] * inv1 * fm;
    for (int c = j; c < 160; c += 64) on[320 + c] = xn[320 + c] * inv2 * fm;
}

extern "C" void kernel_launch(void* const* d_in, const int* in_sizes, int n_in,
                              void* d_out, int out_size, void* d_ws, size_t ws_size,
                              hipStream_t stream) {
    const int*   z    = (const int*)d_in[0];
    const float* mask = (const float*)d_in[1];
    const int*   esrc = (const int*)d_in[2];
    const int*   edst = (const int*)d_in[3];
    const float* ew   = (const float*)d_in[4];
    const float* ev   = (const float*)d_in[5];
    const float* zemb = (const float*)d_in[6];
    const float* Win  = (const float*)d_in[7];
    const float* Wp   = (const float*)d_in[8];
    const float* rW1  = (const float*)d_in[9];
    const float* rb1  = (const float*)d_in[10];
    const float* rW2  = (const float*)d_in[11];
    const float* rb2  = (const float*)d_in[12];
    const float* Wo0  = (const float*)d_in[13];
    const float* Wo1  = (const float*)d_in[14];
    const float* Wo2  = (const float*)d_in[15];
    const float* res  = (const float*)d_in[16];

    const int BN = in_sizes[0];      // 4096
    const int E  = in_sizes[2];      // 131072

    // ---- workspace carve ----
    char* w = (char*)d_ws;
    float* x    = (float*)w; w += (size_t)BN * DIMN * 4;        // 7.86 MB
    float* P    = (float*)w; w += (size_t)BN * 192 * 4;         // 3.15 MB
    float* rtab = (float*)w; w += (size_t)NBLK * NT * 192 * 4;  // 4.72 MB
    float* shf  = (float*)w; w += (size_t)E * 10 * 4;           // 5.24 MB
    int* counts = (int*)w;   w += (size_t)BN * 4;
    int* offs   = (int*)w;   w += (size_t)(BN + 4) * 4;
    int* cursor = (int*)w;   w += (size_t)BN * 4;
    int* perm   = (int*)w;   w += (size_t)E * 4;

    hipMemsetAsync(counts, 0, (size_t)BN * 4, stream);

    k_edge<<<(E + 255) / 256, 256, 0, stream>>>(ew, ev, edst, shf, counts, E);
    k_scan<<<1, 1024, 0, stream>>>(counts, offs, cursor, BN);
    k_perm<<<(E + 255) / 256, 256, 0, stream>>>(edst, cursor, perm, E);
    k_initx<<<BN, 128, 0, stream>>>(z, mask, zemb, Win, x);
    k_rtab<<<NBLK * NT, 64, 0, stream>>>(rW1, rb1, rW2, rb2, rtab);

    for (int b = 0; b < NBLK; ++b) {
        k_proj<<<BN, 192, 0, stream>>>(x, Wp + (size_t)b * M0 * 192, P);
        k_node<<<BN, 64, 0, stream>>>(P, rtab + (size_t)b * NT * 192, shf, ew,
                                      esrc, offs, perm,
                                      Wo0 + (size_t)b * MSGC * M0,
                                      Wo1 + (size_t)b * MSGC * M1,
                                      Wo2 + (size_t)b * MSGC * M2,
                                      res, b, x);
    }

    k_norm<<<BN, 64, 0, stream>>>(x, mask, (float*)d_out);
}

// Round 2
// 287.847 us; speedup vs baseline: 1.1955x; 1.1955x over previous
//
#include <hip/hip_runtime.h>
#include <math.h>

#define M0 128
#define M1 64
#define M2 32
#define DIMN 480      // 128 + 3*64 + 5*32
#define MSGC 64
#define NBLK 3
#define RBFD 32
#define NT 2048       // r-table resolution
#define FCUT 5.0f

// 48-byte dst-sorted edge record: everything the gather loop needs except P/rtab rows
struct __align__(16) ERec {
    int   src;
    int   ti;
    float fr;
    float fc;
    float sh[8];   // sh1..sh8 (sh0 == 1)
};

// ---------- pass 1: count edges per dst ----------
__global__ void k_count(const int* __restrict__ dst, int* __restrict__ counts, int E) {
    int e = blockIdx.x * blockDim.x + threadIdx.x;
    if (e >= E) return;
    atomicAdd(&counts[dst[e]], 1);
}

// ---------- exclusive prefix scan of counts (single block) ----------
__global__ void k_scan(const int* __restrict__ counts, int* __restrict__ offs,
                       int* __restrict__ cursor, int n) {
    __shared__ int buf[4096];
    for (int i = threadIdx.x; i < n; i += blockDim.x) buf[i] = counts[i];
    __syncthreads();
    for (int d = 1; d < n; d <<= 1) {
        int vals[4];
        int k = 0;
        for (int i = threadIdx.x; i < n; i += blockDim.x, ++k)
            vals[k] = (i >= d) ? buf[i - d] : 0;
        __syncthreads();
        k = 0;
        for (int i = threadIdx.x; i < n; i += blockDim.x, ++k)
            buf[i] += vals[k];
        __syncthreads();
    }
    for (int i = threadIdx.x; i < n; i += blockDim.x) {
        int excl = (i == 0) ? 0 : buf[i - 1];
        offs[i] = excl;
        cursor[i] = excl;
    }
    if (threadIdx.x == 0) offs[n] = buf[n - 1];
}

// ---------- pass 2: compute edge features and scatter records into dst order ----------
__global__ void k_build(const float* __restrict__ ew, const float* __restrict__ ev,
                        const int* __restrict__ src, const int* __restrict__ dst,
                        int* __restrict__ cursor, ERec* __restrict__ rec, int E) {
    int e = blockIdx.x * blockDim.x + threadIdx.x;
    if (e >= E) return;
    float len = ew[e];
    float inv = 1.0f / fmaxf(len, 1e-8f);
    float x = ev[e * 3 + 0] * inv;
    float y = ev[e * 3 + 1] * inv;
    float z = ev[e * 3 + 2] * inv;
    const float s3 = 1.7320508075688772f, s5 = 2.23606797749979f, s15 = 3.872983346207417f;
    ERec r;
    r.src = src[e];
    float u = fminf(len, FCUT) * ((float)(NT - 1) / FCUT);
    int ti = (int)u;
    ti = min(ti, NT - 2);
    r.ti = ti;
    r.fr = u - (float)ti;
    float t = fminf(len / FCUT, 1.0f);
    r.fc = 0.5f * (cosf(3.14159265358979323846f * t) + 1.0f);
    r.sh[0] = s3 * x;
    r.sh[1] = s3 * y;
    r.sh[2] = s3 * z;
    r.sh[3] = s15 * x * y;
    r.sh[4] = s15 * y * z;
    r.sh[5] = 0.5f * s5 * (3.0f * z * z - 1.0f);
    r.sh[6] = s15 * x * z;
    r.sh[7] = 0.5f * s15 * (x * x - y * y);
    int p = atomicAdd(&cursor[dst[e]], 1);
    rec[p] = r;
}

// ---------- x init: x[:, :128] = (z_emb[z] @ W_in) * mask ; rest 0 ----------
__global__ __launch_bounds__(128) void k_initx(const int* __restrict__ z,
                                               const float* __restrict__ mask,
                                               const float* __restrict__ zemb,
                                               const float* __restrict__ Win,
                                               float* __restrict__ x) {
    int n = blockIdx.x;
    __shared__ float zf[M0];
    int zi = z[n];
    for (int k = threadIdx.x; k < M0; k += blockDim.x) zf[k] = zemb[zi * M0 + k];
    __syncthreads();
    int j = threadIdx.x;
    float acc = 0.0f;
    for (int k = 0; k < M0; ++k) acc += zf[k] * Win[k * M0 + j];
    float fm = mask[n];
    x[(size_t)n * DIMN + j] = acc * fm;
    for (int t = M0 + j; t < DIMN; t += M0) x[(size_t)n * DIMN + t] = 0.0f;
}

// ---------- r-table: r(len) = silu(rbf(len)@rW1+rb1)@rW2+rb2, len on NT grid ----------
__global__ __launch_bounds__(64) void k_rtab(const float* __restrict__ rW1,
                                             const float* __restrict__ rb1,
                                             const float* __restrict__ rW2,
                                             const float* __restrict__ rb2,
                                             float* __restrict__ rtab) {
    int row = blockIdx.x;           // 0 .. NBLK*NT-1
    int b = row / NT, t = row % NT;
    float len = (float)t * (FCUT / (float)(NT - 1));
    __shared__ float rb[RBFD];
    __shared__ float hh[64];
    int j = threadIdx.x;
    if (j < RBFD) {
        float c = (float)j * (FCUT / (float)(RBFD - 1));
        float w = FCUT / (float)(RBFD - 1);
        float d0 = (fminf(len, FCUT) - c) / w;
        rb[j] = expf(-0.5f * d0 * d0);
    }
    __syncthreads();
    const float* W1 = rW1 + b * RBFD * 64;
    float a = rb1[b * 64 + j];
    for (int k = 0; k < RBFD; ++k) a += rb[k] * W1[k * 64 + j];
    hh[j] = a / (1.0f + expf(-a));    // silu
    __syncthreads();
    const float* W2 = rW2 + b * 64 * 192;
    for (int c = j; c < 192; c += 64) {
        float r = rb2[b * 192 + c];
        for (int k = 0; k < 64; ++k) r += hh[k] * W2[k * 192 + c];
        rtab[((size_t)b * NT + t) * 192 + c] = r;
    }
}

// ---------- node projection: P = x[:, :128] @ Wp[b] ----------
__global__ __launch_bounds__(192) void k_proj(const float* __restrict__ x,
                                              const float* __restrict__ Wp,
                                              float* __restrict__ P) {
    int n = blockIdx.x;
    __shared__ float s[M0];
    for (int k = threadIdx.x; k < M0; k += blockDim.x) s[k] = x[(size_t)n * DIMN + k];
    __syncthreads();
    int j = threadIdx.x;   // 0..191
    float acc = 0.0f;
    for (int k = 0; k < M0; ++k) acc += s[k] * Wp[k * 192 + j];
    P[(size_t)n * 192 + j] = acc;
}

// ---------- per-node message gather + Wo application (4 waves per node) ----------
__global__ __launch_bounds__(256, 8) void k_node(const float* __restrict__ P,
                                                 const float* __restrict__ rtab,
                                                 const ERec* __restrict__ rec,
                                                 const int* __restrict__ offs,
                                                 const float* __restrict__ Wo0,
                                                 const float* __restrict__ Wo1,
                                                 const float* __restrict__ Wo2,
                                                 const float* __restrict__ res_scale, int b,
                                                 float* __restrict__ x) {
    int n = blockIdx.x;
    int t = threadIdx.x;
    int w = t >> 6;        // wave 0..3
    int j = t & 63;
    int e0 = offs[n], e1 = offs[n + 1];
    float m0 = 0.0f;
    float m1a[3] = {0, 0, 0};
    float m2a[5] = {0, 0, 0, 0, 0};
    __shared__ float mbuf[4][576];

    // one-deep software-pipelined edge loop, stride 4 across waves
    int ii = e0 + w;
    bool has = ii < e1;
    float4 c0, c1, c2;
    if (has) {
        const float4* rp = (const float4*)(rec + ii);
        c0 = rp[0]; c1 = rp[1]; c2 = rp[2];
    }
    while (has) {
        int nii = ii + 4;
        bool nhas = nii < e1;
        float4 p0, p1, p2;
        if (nhas) {
            const float4* rp = (const float4*)(rec + nii);
            p0 = rp[0]; p1 = rp[1]; p2 = rp[2];
        }
        int src = __float_as_int(c0.x);
        int ti  = __float_as_int(c0.y);
        float fr = c0.z, fc = c0.w;
        const float* r0 = rtab + (size_t)ti * 192;
        const float* r1 = r0 + 192;
        const float* Ps = P + (size_t)src * 192;

        float ra0 = r0[j],       ra1 = r1[j];
        float rb0 = r0[64 + j],  rb1_ = r1[64 + j];
        float rc0 = r0[128 + j], rc1 = r1[128 + j];
        float pa = Ps[j], pb = Ps[64 + j], pc = Ps[128 + j];

        float ra = ra0 + fr * (ra1 - ra0);
        float w0 = pa * ra * fc;
        m0 += w0;

        float rbv = rb0 + fr * (rb1_ - rb0);
        float w1 = pb * rbv * fc;
        m1a[0] += w1 * c1.x;
        m1a[1] += w1 * c1.y;
        m1a[2] += w1 * c1.z;

        float rcv = rc0 + fr * (rc1 - rc0);
        float w2 = pc * rcv * fc;
        m2a[0] += w2 * c1.w;
        m2a[1] += w2 * c2.x;
        m2a[2] += w2 * c2.y;
        m2a[3] += w2 * c2.z;
        m2a[4] += w2 * c2.w;

        ii = nii; has = nhas;
        c0 = p0; c1 = p1; c2 = p2;
    }

    mbuf[w][j] = m0;
    #pragma unroll
    for (int d = 0; d < 3; ++d) mbuf[w][64 + j * 3 + d] = m1a[d];
    #pragma unroll
    for (int d = 0; d < 5; ++d) mbuf[w][256 + j * 5 + d] = m2a[d];
    __syncthreads();

    // reduce 4 partials into mbuf[0]
    for (int c = t; c < 576; c += 256)
        mbuf[0][c] = mbuf[0][c] + mbuf[1][c] + mbuf[2][c] + mbuf[3][c];
    __syncthreads();

    float rs = res_scale[b];
    float* xn = x + (size_t)n * DIMN;

    // 480 outputs, each a 64-length dot over an msum segment
    for (int o = t; o < DIMN; o += 256) {
        float acc = 0.0f;
        if (o < M0) {
            #pragma unroll 8
            for (int c = 0; c < 64; ++c) acc += mbuf[0][c] * Wo0[c * M0 + o];
        } else if (o < M0 + 3 * M1) {
            int q = o - M0;
            int k = q / 3, d = q - 3 * k;
            #pragma unroll 8
            for (int c = 0; c < 64; ++c) acc += mbuf[0][64 + c * 3 + d] * Wo1[c * M1 + k];
        } else {
            int q = o - (M0 + 3 * M1);
            int k = q / 5, d = q - 5 * k;
            #pragma unroll 8
            for (int c = 0; c < 64; ++c) acc += mbuf[0][256 + c * 5 + d] * Wo2[c * M2 + k];
        }
        xn[o] += rs * acc;
    }
}

// ---------- final irrep norm + mask ----------
__global__ __launch_bounds__(64) void k_norm(const float* __restrict__ x,
                                             const float* __restrict__ mask,
                                             float* __restrict__ out) {
    int n = blockIdx.x;
    int j = threadIdx.x;
    const float* xn = x + (size_t)n * DIMN;
    float s0 = 0, s1 = 0, s2 = 0;
    for (int c = j; c < 128; c += 64) { float v = xn[c]; s0 += v * v; }
    for (int c = j; c < 192; c += 64) { float v = xn[128 + c]; s1 += v * v; }
    for (int c = j; c < 160; c += 64) { float v = xn[320 + c]; s2 += v * v; }
    for (int d = 32; d > 0; d >>= 1) {
        s0 += __shfl_down(s0, d);
        s1 += __shfl_down(s1, d);
        s2 += __shfl_down(s2, d);
    }
    __shared__ float inv0, inv1, inv2;
    if (j == 0) {
        inv0 = rsqrtf(s0 / (float)M0 + 1e-6f);
        inv1 = rsqrtf(s1 / (float)M1 + 1e-6f);
        inv2 = rsqrtf(s2 / (float)M2 + 1e-6f);
    }
    __syncthreads();
    float fm = mask[n];
    float* on = out + (size_t)n * DIMN;
    for (int c = j; c < 128; c += 64) on[c] = xn[c] * inv0 * fm;
    for (int c = j; c < 192; c += 64) on[128 + c] = xn[128 + c] * inv1 * fm;
    for (int c = j; c < 160; c += 64) on[320 + c] = xn[320 + c] * inv2 * fm;
}

extern "C" void kernel_launch(void* const* d_in, const int* in_sizes, int n_in,
                              void* d_out, int out_size, void* d_ws, size_t ws_size,
                              hipStream_t stream) {
    const int*   z    = (const int*)d_in[0];
    const float* mask = (const float*)d_in[1];
    const int*   esrc = (const int*)d_in[2];
    const int*   edst = (const int*)d_in[3];
    const float* ew   = (const float*)d_in[4];
    const float* ev   = (const float*)d_in[5];
    const float* zemb = (const float*)d_in[6];
    const float* Win  = (const float*)d_in[7];
    const float* Wp   = (const float*)d_in[8];
    const float* rW1  = (const float*)d_in[9];
    const float* rb1  = (const float*)d_in[10];
    const float* rW2  = (const float*)d_in[11];
    const float* rb2  = (const float*)d_in[12];
    const float* Wo0  = (const float*)d_in[13];
    const float* Wo1  = (const float*)d_in[14];
    const float* Wo2  = (const float*)d_in[15];
    const float* res  = (const float*)d_in[16];

    const int BN = in_sizes[0];      // 4096
    const int E  = in_sizes[2];      // 131072

    // ---- workspace carve ----
    char* w = (char*)d_ws;
    float* x    = (float*)w; w += (size_t)BN * DIMN * 4;        // 7.86 MB
    float* P    = (float*)w; w += (size_t)BN * 192 * 4;         // 3.15 MB
    float* rtab = (float*)w; w += (size_t)NBLK * NT * 192 * 4;  // 4.72 MB
    ERec* rec   = (ERec*)w;  w += (size_t)E * sizeof(ERec);     // 6.29 MB
    int* counts = (int*)w;   w += (size_t)BN * 4;
    int* offs   = (int*)w;   w += (size_t)(BN + 4) * 4;
    int* cursor = (int*)w;   w += (size_t)BN * 4;

    hipMemsetAsync(counts, 0, (size_t)BN * 4, stream);

    k_count<<<(E + 255) / 256, 256, 0, stream>>>(edst, counts, E);
    k_scan<<<1, 1024, 0, stream>>>(counts, offs, cursor, BN);
    k_build<<<(E + 255) / 256, 256, 0, stream>>>(ew, ev, esrc, edst, cursor, rec, E);
    k_initx<<<BN, 128, 0, stream>>>(z, mask, zemb, Win, x);
    k_rtab<<<NBLK * NT, 64, 0, stream>>>(rW1, rb1, rW2, rb2, rtab);

    for (int b = 0; b < NBLK; ++b) {
        k_proj<<<BN, 192, 0, stream>>>(x, Wp + (size_t)b * M0 * 192, P);
        k_node<<<BN, 256, 0, stream>>>(P, rtab + (size_t)b * NT * 192, rec, offs,
                                       Wo0 + (size_t)b * MSGC * M0,
                                       Wo1 + (size_t)b * MSGC * M1,
                                       Wo2 + (size_t)b * MSGC * M2,
                                       res, b, x);
    }

    k_norm<<<BN, 64, 0, stream>>>(x, mask, (float*)d_out);
}